// Round 9
// baseline (237.805 us; speedup 1.0000x reference)
//
#include <hip/hip_runtime.h>
#include <hip/hip_bf16.h>
#include <stdint.h>

#define N_PTS 16384
#define M_PTS 2048

#define GLOBAL_AS __attribute__((address_space(1)))
#define LDS_AS    __attribute__((address_space(3)))

typedef __bf16 bf16x8 __attribute__((ext_vector_type(8)));
typedef float  f32x4  __attribute__((ext_vector_type(4)));

// ---------------------------------------------------------------------------
// Kernel 1: K[i][j] = exp(-||x_i - z_j||_1) -> bf16.
// 64 rows/block (grid 256): z hoisted once into 32 VGPRs per thread and
// amortized over 64 rows; stores bf16x8 (16 B/lane contiguous).
// ---------------------------------------------------------------------------
__global__ __launch_bounds__(256) void laplace_k(
    const float* __restrict__ x, const float* __restrict__ z,
    __hip_bfloat16* __restrict__ Kout) {
  const int t  = threadIdx.x;
  const int i0 = blockIdx.x * 64;
  const int j0 = t * 8;
  float4 zv[8];
#pragma unroll
  for (int e = 0; e < 8; ++e)
    zv[e] = reinterpret_cast<const float4*>(z)[j0 + e];
#pragma unroll 4
  for (int rr = 0; rr < 64; ++rr) {
    const int i = i0 + rr;
    const float4 xv = *reinterpret_cast<const float4*>(x + (size_t)i * 4);
    bf16x8 outv;
#pragma unroll
    for (int e = 0; e < 8; ++e) {
      const float l1 = fabsf(xv.x - zv[e].x) + fabsf(xv.y - zv[e].y) +
                       fabsf(xv.z - zv[e].z) + fabsf(xv.w - zv[e].w);
      outv[e] = (__bf16)__expf(-l1);
    }
    *reinterpret_cast<bf16x8*>(Kout + (size_t)i * M_PTS + j0) = outv;
  }
}

// ---------------------------------------------------------------------------
// Kernel 2: Bt[j][k] = chol_inv[k][j] -> bf16 (tiled transpose).
// ---------------------------------------------------------------------------
__global__ __launch_bounds__(256) void transpose_cast(
    const float* __restrict__ B, __hip_bfloat16* __restrict__ Bt) {
  __shared__ float tile[32][33];
  const int bj = blockIdx.x * 32;
  const int bk = blockIdx.y * 32;
  const int tx = threadIdx.x, ty = threadIdx.y;
#pragma unroll
  for (int yy = ty; yy < 32; yy += 8)
    tile[yy][tx] = B[(size_t)(bk + yy) * M_PTS + bj + tx];
  __syncthreads();
#pragma unroll
  for (int yy = ty; yy < 32; yy += 8)
    Bt[(size_t)(bj + yy) * M_PTS + bk + tx] = __float2bfloat16(tile[tx][yy]);
}

// ---------------------------------------------------------------------------
// Kernel 3: C = K @ U (triangular). HALVED 8-phase template: 128x128 tile,
// BK=64, 4 waves (2Mx2N), LDS 64 KiB -> **2 independent blocks per CU**
// (was 256x256/128KiB/1 block). Rationale (round-7 data): 1 block/CU puts
// all waves in one barrier group -> ~900 cyc/phase dead stall; a second
// resident block's MFMAs fill those stalls (m114 mechanism) and its
// prologue hides under our compute. Ledger/swizzle are op-for-op identical
// to the verified 256^2 version (each STG still = 2 gload_lds; 128-B LDS
// rows; same XOR keys), so race-freedom carries over.
//
// LDS 64 KiB: buf(2) x 32 KiB: A0(rows0-63)|A1(64-127)|B0|B1, 8 KiB each.
// Swizzle (T2, rule 21): LDS[row][colb] holds global col-byte
//   colb ^ ((row&7)<<4); writer linear dest + pre-swizzled source col;
//   reader XORs the same. (SQ_LDS_BANK_CONFLICT measured 0.)
// Ledger per frame (tiles t@buf0 P1-4, t+1@buf1 P5-8):
//   P1: A0(t+1)->buf1   P2: A1(t+1), B0(t+2)->buf0   P3: B1(t+2)->buf0
//   P4: vmcnt(4) [last frame vmcnt(0)]
//   P5: A0(t+2)->buf0   P6: A1(t+2), B0(t+3)->buf1   P7: B1(t+3)->buf1
//   P8: vmcnt(4)
// Phase body: ds_reads; stages; [vmcnt]; s_barrier; lgkmcnt(0);
//   sched_barrier(0); setprio(1); 8 MFMA (m=Q2); setprio(0); s_barrier.
// Triangular: jt 0..15, kLimit=(jt+1)*128, NT=(jt+1)*2 (even; NT=2 ok:
// s2=false -> P4 vmcnt(0), P5-8 no stages). 5.6% less work than 256-wide.
// Dispatch: bids 0-1023 heavy jt=15..8, 1024-2047 light jt=0..7.
// ---------------------------------------------------------------------------
__global__ __launch_bounds__(256, 2) void gemm_bf16_8ph(
    const __hip_bfloat16* __restrict__ A,   // [N][2048] bf16 (K matrix)
    const __hip_bfloat16* __restrict__ Bt,  // [2048][2048] bf16, Bt[j][k]
    float* __restrict__ Cmat) {             // [N][2048] fp32
  __shared__ alignas(16) char ldsBuf[65536];
  char* ldsC = ldsBuf;

  const int tid  = threadIdx.x;
  const int lane = tid & 63;
  const int wid  = tid >> 6;  // 0..3
  const int wm   = wid >> 1;  // 0..1 -> 64-row block
  const int wn   = wid & 1;   // 0..1 -> 64-col block
  const int q    = lane >> 4;
  const int r    = lane & 15;

  const int bid = blockIdx.x;
  int it, jt;
  if (bid < 1024) { jt = 15 - (bid >> 7); it = bid & 127; }
  else            { jt = (bid - 1024) >> 7; it = (bid - 1024) & 127; }
  const int iBase = it * 128;
  const int jBase = jt * 128;
  const int NT = (jt + 1) * 2;  // K-tiles of 64; even, 2..32

  // ---- staging source pointers (pre-swizzled column, rule 21) ----
  const int srow  = tid >> 3;   // 0..31
  const int scolE = ((tid & 7) ^ ((tid >> 3) & 7)) * 8;
  const __hip_bfloat16* aGp0 = A  + (size_t)(iBase + srow)      * M_PTS + scolE;
  const __hip_bfloat16* aGp1 = A  + (size_t)(iBase + 64 + srow) * M_PTS + scolE;
  const __hip_bfloat16* bGp0 = Bt + (size_t)(jBase + srow)      * M_PTS + scolE;
  const __hip_bfloat16* bGp1 = Bt + (size_t)(jBase + 64 + srow) * M_PTS + scolE;

  // ---- LDS read bases (swizzled), kk=0 / kk=1 variants ----
  // A rows wm*64 + m*16 + r live in half A[wm]; byte = (m*16+r)*128.
  const int colK0 = (q * 16) ^ ((r & 7) << 4);
  const char* aRd0 = ldsC + wm * 8192 + r * 128 + colK0;
  const char* aRd1 = ldsC + wm * 8192 + r * 128 + (colK0 ^ 64);
  const char* bRd0 = ldsC + 16384 + wn * 8192 + r * 128 + colK0;
  const char* bRd1 = ldsC + 16384 + wn * 8192 + r * 128 + (colK0 ^ 64);

  f32x4 acc[4][4] = {};
  bf16x8 bF[4][2];

// one STG = 2 gload_lds ops of 4 KiB (32 rows each): op2 at +32 rows.
#define STG(GP, LOFF, KT)                                                    \
  do {                                                                       \
    __builtin_amdgcn_global_load_lds(                                        \
        (const GLOBAL_AS void*)((GP) + (size_t)(KT)*64),                     \
        (LDS_AS void*)(ldsC + (LOFF) + tid * 16), 16, 0, 0);                 \
    __builtin_amdgcn_global_load_lds(                                        \
        (const GLOBAL_AS void*)((GP) + (size_t)(KT)*64 + 32 * M_PTS),        \
        (LDS_AS void*)(ldsC + (LOFF) + 4096 + tid * 16), 16, 0, 0);          \
  } while (0)
#define STG_A0(BUF, KT) STG(aGp0, (BUF)*32768, KT)
#define STG_A1(BUF, KT) STG(aGp1, (BUF)*32768 + 8192, KT)
#define STG_B0(BUF, KT) STG(bGp0, (BUF)*32768 + 16384, KT)
#define STG_B1(BUF, KT) STG(bGp1, (BUF)*32768 + 24576, KT)

#define VM4 asm volatile("s_waitcnt vmcnt(4)" ::: "memory")
#define VM0 asm volatile("s_waitcnt vmcnt(0)" ::: "memory")
#define VMNONE (void)0

#define PHASE(Q2, BOFF, READB, VMW, ...)                                     \
  {                                                                          \
    if (READB) {                                                             \
      _Pragma("unroll") for (int nn = 0; nn < 4; ++nn) {                     \
        bF[nn][0] = *(const bf16x8*)(bRd0 + (BOFF) + nn * 2048);             \
        bF[nn][1] = *(const bf16x8*)(bRd1 + (BOFF) + nn * 2048);             \
      }                                                                      \
    }                                                                        \
    bf16x8 aFk0 = *(const bf16x8*)(aRd0 + (BOFF) + (Q2)*2048);               \
    bf16x8 aFk1 = *(const bf16x8*)(aRd1 + (BOFF) + (Q2)*2048);               \
    __VA_ARGS__;                                                             \
    VMW;                                                                     \
    __builtin_amdgcn_s_barrier();                                            \
    asm volatile("s_waitcnt lgkmcnt(0)" ::: "memory");                       \
    __builtin_amdgcn_sched_barrier(0);                                       \
    __builtin_amdgcn_s_setprio(1);                                           \
    _Pragma("unroll") for (int nn = 0; nn < 4; ++nn) {                       \
      acc[Q2][nn] = __builtin_amdgcn_mfma_f32_16x16x32_bf16(                 \
          aFk0, bF[nn][0], acc[Q2][nn], 0, 0, 0);                            \
      acc[Q2][nn] = __builtin_amdgcn_mfma_f32_16x16x32_bf16(                 \
          aFk1, bF[nn][1], acc[Q2][nn], 0, 0, 0);                            \
    }                                                                        \
    __builtin_amdgcn_s_setprio(0);                                           \
    __builtin_amdgcn_s_barrier();                                            \
  }

  // ---- prologue: tile0 complete + tile1's B; allow B(1) in flight ----
  STG_A0(0, 0); STG_A1(0, 0); STG_B0(0, 0); STG_B1(0, 0);
  STG_B0(1, 1); STG_B1(1, 1);
  VM4;
  __builtin_amdgcn_s_barrier();

  for (int t = 0; t < NT; t += 2) {
    const bool s2 = (t + 2) < NT;  // == (t+3 < NT) since NT,t even
    // P1..P4: tile t from buf0
    PHASE(0, 0, true,  VMNONE, { STG_A0(1, t + 1); });
    PHASE(1, 0, false, VMNONE, { STG_A1(1, t + 1); if (s2) STG_B0(0, t + 2); });
    PHASE(2, 0, false, VMNONE, { if (s2) STG_B1(0, t + 2); });
    if (s2) { PHASE(3, 0, false, VM4, {}); }
    else    { PHASE(3, 0, false, VM0, {}); }
    // P5..P8: tile t+1 from buf1
    PHASE(0, 32768, true,  VMNONE, { if (s2) STG_A0(0, t + 2); });
    PHASE(1, 32768, false, VMNONE, { if (s2) { STG_A1(0, t + 2); STG_B0(1, t + 3); } });
    PHASE(2, 32768, false, VMNONE, { if (s2) STG_B1(1, t + 3); });
    PHASE(3, 32768, false, VM4, {});
  }

  // ---- epilogue: C/D layout col = lane&15, row = q*4 + v [m89] ----
  const int crow = iBase + wm * 64 + q * 4;
  const int ccol = jBase + wn * 64 + r;
#pragma unroll
  for (int m = 0; m < 4; ++m)
#pragma unroll
    for (int nn = 0; nn < 4; ++nn)
#pragma unroll
      for (int v = 0; v < 4; ++v)
        Cmat[(size_t)(crow + m * 16 + v) * M_PTS + (ccol + nn * 16)] =
            acc[m][nn][v];
}

extern "C" void kernel_launch(void* const* d_in, const int* in_sizes, int n_in,
                              void* d_out, int out_size, void* d_ws,
                              size_t ws_size, hipStream_t stream) {
  const float* x    = (const float*)d_in[0];
  const float* z    = (const float*)d_in[1];
  const float* chol = (const float*)d_in[2];
  float* out = (float*)d_out;

  __hip_bfloat16* Kbf = (__hip_bfloat16*)d_ws;                        // 64 MB
  __hip_bfloat16* Bt  = (__hip_bfloat16*)((char*)d_ws +
                        (size_t)N_PTS * M_PTS * sizeof(__hip_bfloat16)); // 8 MB

  laplace_k<<<dim3(N_PTS / 64), 256, 0, stream>>>(x, z, Kbf);
  transpose_cast<<<dim3(M_PTS / 32, M_PTS / 32), dim3(32, 8), 0, stream>>>(
      chol, Bt);
  gemm_bf16_8ph<<<dim3(2048), 256, 0, stream>>>(Kbf, Bt, out);
}